// Round 13
// baseline (237.933 us; speedup 1.0000x reference)
//
#include <hip/hip_runtime.h>

#define TAILB 12.0f

typedef _Float16 half8 __attribute__((ext_vector_type(8)));
typedef _Float16 half4 __attribute__((ext_vector_type(4)));
typedef __fp16 fp16x2 __attribute__((ext_vector_type(2)));   // pkrtz return type
typedef __attribute__((ext_vector_type(4))) float f32x4;
typedef __attribute__((ext_vector_type(2))) float f32x2;

#define MFMAH __builtin_amdgcn_mfma_f32_16x16x32_f16

// soft phase fence (v22-proven): compile-time scheduling structure without
// runtime drains. mask 0x24 = SALU | VMEM_READ may cross; VALU/MFMA/DS
// pinned. Same-wave DS FIFO order guarantees correctness (v19).
#define SOFT_SYNC() __builtin_amdgcn_sched_barrier(0x24)

// fast softplus: log(1+e^z); abs err ~2^-24
__device__ __forceinline__ float softplus_f(float z) {
    return (z > 15.f) ? z : __logf(1.f + __expf(z));
}

// unscaled fp16 2-term split (v23-verified): RNE main, raw residual.
__device__ __forceinline__ void split2h(float v, _Float16& o0, _Float16& o1) {
    _Float16 h0 = (_Float16)v;
    float r1 = v - (float)h0;
    o0 = h0;
    o1 = (_Float16)r1;
}

// pkrtz-based unscaled split of 4 values -> two packed half4 planes
__device__ __forceinline__ void split4_ns(const float* v, half4& p0, half4& p1) {
    fp16x2 lo = __builtin_amdgcn_cvt_pkrtz(v[0], v[1]);
    fp16x2 hi = __builtin_amdgcn_cvt_pkrtz(v[2], v[3]);
    float r0 = v[0] - (float)lo.x;
    float r1 = v[1] - (float)lo.y;
    float r2 = v[2] - (float)hi.x;
    float r3 = v[3] - (float)hi.y;
    fp16x2 rlo = __builtin_amdgcn_cvt_pkrtz(r0, r1);
    fp16x2 rhi = __builtin_amdgcn_cvt_pkrtz(r2, r3);
    p0 = (half4){(_Float16)lo.x, (_Float16)lo.y, (_Float16)hi.x, (_Float16)hi.y};
    p1 = (half4){(_Float16)rlo.x, (_Float16)rlo.y, (_Float16)rhi.x, (_Float16)rhi.y};
}

// ---------------- prep: identical layout to v10..v23 ----------------
__global__ __launch_bounds__(256)
void prep_v24(const float* __restrict__ W1, const float* __restrict__ b1,
              const float* __restrict__ W2, const float* __restrict__ W3,
              _Float16* __restrict__ W2F, _Float16* __restrict__ W3F,
              float4* __restrict__ w1p)
{
    int id = blockIdx.x * 256 + threadIdx.x;
    if (id < 65536) {
        int j = id & 7, ln = (id >> 3) & 63, tile = id >> 9;
        int cs = tile & 3, t = (tile >> 2) & 1, wv = (tile >> 3) & 3, l = tile >> 5;
        int n = 32 * wv + 16 * t + (ln & 15);
        int k = 32 * cs + 8 * (ln >> 4) + j;
        _Float16 a, b;
        split2h(W2[l * 16384 + n * 128 + k], a, b);
        W2F[(tile * 2 + 0) * 512 + ln * 8 + j] = a;
        W2F[(tile * 2 + 1) * 512 + ln * 8 + j] = b;
    } else if (id < 90112) {
        int t2 = id - 65536;
        int j = t2 & 7, ln = (t2 >> 3) & 63, tile3 = t2 >> 9;
        int cs = tile3 & 3, q = tile3 >> 2;
        int wv = q % 3, l = q / 3;
        int p = 16 * wv + (ln & 15);
        int n = 32 * cs + 8 * (ln >> 4) + j;
        float v = (p < 46) ? W3[l * 5888 + p * 128 + n] : 0.f;
        _Float16 a, b;
        split2h(v, a, b);
        W3F[(tile3 * 2 + 0) * 512 + ln * 8 + j] = a;
        W3F[(tile3 * 2 + 1) * 512 + ln * 8 + j] = b;
    } else if (id < 90624) {
        int t = id - 90112;
        int l = t >> 7, k = t & 127;
        float4 v;
        v.x = W1[l * 384 + k * 3 + 0];
        v.y = W1[l * 384 + k * 3 + 1];
        v.z = W1[l * 384 + k * 3 + 2];
        v.w = b1[l * 128 + k];
        w1p[t] = v;
    }
}

// v24 = v23 (best: 192.0us) + packed dual-FP32 phase-1. The h1 compute is
// the largest VALU block (1024 scalar fma/max per wave); the two samples
// (s, s+16) share the same w4 chain -- a perfect v_pk_fma_f32 pair.
// __builtin_elementwise_fma on float2 lowers to llvm.fma.v2f32 ->
// v_pk_fma_f32 (gfx90a+), halving that block's issue cost. Per-half IEEE
// fma semantics and nesting order identical to v23 -> bit-identical.
__global__ __launch_bounds__(64)
void rqs_v24(const float* __restrict__ inp, const float* __restrict__ cond,
             const _Float16* __restrict__ W2F, const _Float16* __restrict__ W3F,
             const float4* __restrict__ w1p,
             const float* __restrict__ b2, const float* __restrict__ b3,
             float* __restrict__ out, int B)
{
    __shared__ __align__(16) char P[8192];     // h2 planeA + planeB @4096; pbuf overlays
    __shared__ float xbuf[32][5];

    char* plw = P;
    const char* pl = P;

    const int ln   = threadIdx.x;              // 0..63
    const int base = blockIdx.x * 32;
    const int sm   = ln & 15;
    const int qd   = ln >> 4;                  // 0..3
    const int s1   = ln & 31;                  // sample slot
    const int hi   = ln >> 5;                  // half index

    // b-frag read addresses (v16): row = 16st+sm, slot = (4csl+qd)^(row&7)
    int rdK[2][2];
    #pragma unroll
    for (int st = 0; st < 2; ++st)
        #pragma unroll
        for (int csl = 0; csl < 2; ++csl) {
            int row = 16 * st + sm;
            rdK[st][csl] = row * 128 + (((4 * csl + qd) ^ (row & 7)) << 4);
        }

    if (ln < 32) {
        float4 xi = reinterpret_cast<const float4*>(inp)[base + ln];
        xbuf[ln][0] = xi.x; xbuf[ln][1] = xi.y;
        xbuf[ln][2] = xi.z; xbuf[ln][3] = xi.w;
        xbuf[ln][4] = cond[base + ln];
    }
    float ladreg = 0.f;
    SOFT_SYNC();

    #pragma unroll 1
    for (int l = 0; l < 4; ++l) {
        int mi0, mi1, ii0, ii1;
        switch (l) {
            case 0:  mi0 = 0; mi1 = 2; ii0 = 1; ii1 = 3; break;
            case 1:  mi0 = 1; mi1 = 3; ii0 = 0; ii1 = 2; break;
            case 2:  mi0 = 0; mi1 = 1; ii0 = 2; ii1 = 3; break;
            default: mi0 = 2; mi1 = 3; ii0 = 0; ii1 = 1; break;
        }

        // ---- phase 1: h1 in B-frag layout, packed dual-FP32 over (st0,st1) ----
        half8 bf[2][4][2];                     // [st][cs][plane]
        {
            f32x2 m0p = {xbuf[sm][mi0],      xbuf[16 + sm][mi0]};
            f32x2 m1p = {xbuf[sm][mi1],      xbuf[16 + sm][mi1]};
            f32x2 ccp = {xbuf[sm][4],        xbuf[16 + sm][4]};
            const float4* w1l = w1p + l * 128;
            #pragma unroll
            for (int cs = 0; cs < 4; ++cs) {
                float v0[8], v1[8];
                #pragma unroll
                for (int j = 0; j < 8; ++j) {
                    float4 w4 = w1l[32 * cs + 8 * qd + j];   // shared by both samples
                    f32x2 a = {w4.w, w4.w};
                    a = __builtin_elementwise_fma((f32x2){w4.z, w4.z}, ccp, a);
                    a = __builtin_elementwise_fma((f32x2){w4.y, w4.y}, m1p, a);
                    a = __builtin_elementwise_fma((f32x2){w4.x, w4.x}, m0p, a);
                    a = __builtin_elementwise_max(a, (f32x2){0.f, 0.f});
                    v0[j] = a.x;
                    v1[j] = a.y;
                }
                half4 a0, a1, b0h, b1h;
                split4_ns(v0, a0, a1);
                split4_ns(v0 + 4, b0h, b1h);
                bf[0][cs][0] = (half8){a0.x, a0.y, a0.z, a0.w, b0h.x, b0h.y, b0h.z, b0h.w};
                bf[0][cs][1] = (half8){a1.x, a1.y, a1.z, a1.w, b1h.x, b1h.y, b1h.z, b1h.w};
                split4_ns(v1, a0, a1);
                split4_ns(v1 + 4, b0h, b1h);
                bf[1][cs][0] = (half8){a0.x, a0.y, a0.z, a0.w, b0h.x, b0h.y, b0h.z, b0h.w};
                bf[1][cs][1] = (half8){a1.x, a1.y, a1.z, a1.w, b1h.x, b1h.y, b1h.z, b1h.w};
            }
        }

        // ---- GEMM2: B from registers; single chained accumulator (v23) ----
        half8 bf3[2][4][2];                    // [st][cs][plane] -- full h2 in regs
        const half8* W2F8 = (const half8*)W2F;
        #pragma unroll
        for (int ntg = 0; ntg < 2; ++ntg) {
            #pragma unroll 1
            for (int ntl = 0; ntl < 4; ++ntl) {
                int nt = 4 * ntg + ntl;        // n-tile 0..7
                f32x4 acc[2];                  // [st]
                float4 bias = *(const float4*)(b2 + l * 128 + nt * 16 + 4 * qd);
                #pragma unroll
                for (int st = 0; st < 2; ++st)
                    acc[st] = (f32x4){bias.x, bias.y, bias.z, bias.w};
                __builtin_amdgcn_s_setprio(1);
                #pragma unroll
                for (int cs = 0; cs < 4; ++cs) {
                    int tile = l * 8 + nt;
                    half8 A0 = W2F8[((tile * 4 + cs) * 2 + 0) * 64 + ln];
                    half8 A1 = W2F8[((tile * 4 + cs) * 2 + 1) * 64 + ln];
                    #pragma unroll
                    for (int st = 0; st < 2; ++st) {
                        acc[st] = MFMAH(A0, bf[st][cs][0], acc[st], 0, 0, 0);
                        acc[st] = MFMAH(A0, bf[st][cs][1], acc[st], 0, 0, 0);
                        acc[st] = MFMAH(A1, bf[st][cs][0], acc[st], 0, 0, 0);
                    }
                }
                __builtin_amdgcn_s_setprio(0);
                // h2 epilogue: relu + unscaled split, write planes
                #pragma unroll
                for (int st = 0; st < 2; ++st) {
                    float v[4];
                    #pragma unroll
                    for (int r = 0; r < 4; ++r)
                        v[r] = fmaxf(acc[st][r], 0.f);
                    half4 p0, p1;
                    split4_ns(v, p0, p1);
                    int row = 16 * st + sm;
                    int gl  = 2 * ntl + (qd >> 1);   // local n-group in [0,8)
                    char* wp = plw + row * 128 + ((gl ^ (row & 7)) << 4) + ((qd & 1) << 3);
                    *(half4*)(wp)        = p0;
                    *(half4*)(wp + 4096) = p1;
                }
            }
            SOFT_SYNC();   // h2 n-half ready (DS order; no drain)
            #pragma unroll
            for (int st = 0; st < 2; ++st)
                #pragma unroll
                for (int csl = 0; csl < 2; ++csl) {
                    bf3[st][2 * ntg + csl][0] = *(const half8*)(pl + rdK[st][csl]);
                    bf3[st][2 * ntg + csl][1] = *(const half8*)(pl + rdK[st][csl] + 4096);
                }
            SOFT_SYNC();   // reads ordered before next-half writes (DS order)
        }

        // ---- GEMM3: single chained accumulator; pv = acc directly ----
        const half8* W3F8 = (const half8*)W3F;
        #pragma unroll 1
        for (int pt = 0; pt < 3; ++pt) {
            f32x4 a3[2];
            #pragma unroll
            for (int st = 0; st < 2; ++st)
                a3[st] = (f32x4){0.f, 0.f, 0.f, 0.f};
            __builtin_amdgcn_s_setprio(1);
            #pragma unroll
            for (int cs = 0; cs < 4; ++cs) {
                int q = (l * 3 + pt) * 4 + cs;
                half8 A0 = W3F8[(q * 2 + 0) * 64 + ln];
                half8 A1 = W3F8[(q * 2 + 1) * 64 + ln];
                #pragma unroll
                for (int st = 0; st < 2; ++st) {
                    a3[st] = MFMAH(A0, bf3[st][cs][0], a3[st], 0, 0, 0);
                    a3[st] = MFMAH(A0, bf3[st][cs][1], a3[st], 0, 0, 0);
                    a3[st] = MFMAH(A1, bf3[st][cs][0], a3[st], 0, 0, 0);
                }
            }
            __builtin_amdgcn_s_setprio(0);
            #pragma unroll
            for (int st = 0; st < 2; ++st) {
                float4 pv;
                pv.x = a3[st][0];
                pv.y = a3[st][1];
                pv.z = a3[st][2];
                pv.w = a3[st][3];
                *(float4*)(plw + (16 * st + sm) * 208 + (16 * pt + 4 * qd) * 4) = pv;
            }
        }
        SOFT_SYNC();   // params visible (DS order; no drain)

        // ---- spline: all 64 lanes, one spline each: f = hi, s = s1 ----
        {
            const float* b3l = b3 + l * 46;
            const float4* prow = (const float4*)(pl + s1 * 208);
            float pr[23];
            #pragma unroll
            for (int i = 0; i < 12; ++i) {
                float4 q = prow[i];
                pr[2 * i] = (hi ? q.y : q.x) + b3l[4 * i + hi];
                if (2 * i + 1 < 23)
                    pr[2 * i + 1] = (hi ? q.w : q.z) + b3l[4 * i + 2 + hi];
            }

            float xin = xbuf[s1][hi == 0 ? ii0 : ii1];

            float d[9];
            d[0] = 1.f; d[8] = 1.f;
            #pragma unroll
            for (int k = 1; k < 8; ++k) d[k] = 1e-6f + softplus_f(pr[16 + k - 1]);

            bool inside = (xin >= -TAILB) && (xin <= TAILB);
            float xc = fminf(fmaxf(xin, -TAILB), TAILB);

            float mw = pr[0], mh = pr[8];
            #pragma unroll
            for (int k = 1; k < 8; ++k) { mw = fmaxf(mw, pr[k]); mh = fmaxf(mh, pr[8 + k]); }
            float ew[8], eh[8], swm = 0.f, shm = 0.f;
            #pragma unroll
            for (int k = 0; k < 8; ++k) {
                ew[k] = __expf(pr[k] - mw);     swm += ew[k];
                eh[k] = __expf(pr[8 + k] - mh); shm += eh[k];
            }
            const float c1 = 1.f - 8e-6f;
            float isw = __fdividef(c1, swm), ish = __fdividef(c1, shm);

            float cum_w = 0.f, cum_h = 0.f;
            float cwk = -TAILB, chk = -TAILB;
            float s_cw = -TAILB, s_w = 2.f * TAILB, s_ch = -TAILB, s_h = 2.f * TAILB;
            float s_d0 = 1.f, s_d1 = d[1];
            #pragma unroll
            for (int k = 0; k < 8; ++k) {
                cum_w += fmaf(ew[k], isw, 1e-6f);
                cum_h += fmaf(eh[k], ish, 1e-6f);
                float cwn = (k == 7) ? TAILB : fmaf(2.f * TAILB, cum_w, -TAILB);
                float chn = (k == 7) ? TAILB : fmaf(2.f * TAILB, cum_h, -TAILB);
                bool ge = (xc >= cwk);
                s_cw = ge ? cwk : s_cw;  s_w = ge ? (cwn - cwk) : s_w;
                s_ch = ge ? chk : s_ch;  s_h = ge ? (chn - chk) : s_h;
                s_d0 = ge ? d[k] : s_d0; s_d1 = ge ? d[k + 1] : s_d1;
                cwk = cwn; chk = chn;
            }

            float rw    = __fdividef(1.f, s_w);
            float th    = (xc - s_cw) * rw;
            float delta = s_h * rw;
            float omt   = 1.f - th;
            float tomt  = th * omt;
            float num   = s_h * fmaf(delta, th * th, s_d0 * tomt);
            float den   = fmaf(s_d0 + s_d1 - 2.f * delta, tomt, delta);
            float y     = s_ch + __fdividef(num, den);
            float dnum  = delta * delta * (s_d1 * th * th + 2.f * delta * tomt + s_d0 * omt * omt);
            float lad   = __logf(dnum) - 2.f * __logf(den);

            xbuf[s1][hi == 0 ? ii0 : ii1] = inside ? y : xin;
            ladreg += inside ? lad : 0.f;
        }
        SOFT_SYNC();   // x updated + pbuf reads ordered before next layer's writes
    } // l

    float lsum = ladreg + __shfl(ladreg, (ln + 32) & 63, 64);
    if (ln < 32) {
        float4 xo;
        xo.x = xbuf[ln][0]; xo.y = xbuf[ln][1];
        xo.z = xbuf[ln][2]; xo.w = xbuf[ln][3];
        reinterpret_cast<float4*>(out)[base + ln] = xo;
        out[(size_t)B * 4 + base + ln] = lsum;
    }
}

extern "C" void kernel_launch(void* const* d_in, const int* in_sizes, int n_in,
                              void* d_out, int out_size, void* d_ws, size_t ws_size,
                              hipStream_t stream) {
    const float* inp  = (const float*)d_in[0];
    const float* cond = (const float*)d_in[1];
    const float* W1   = (const float*)d_in[2];
    const float* b1   = (const float*)d_in[3];
    const float* W2   = (const float*)d_in[4];
    const float* b2   = (const float*)d_in[5];
    const float* W3   = (const float*)d_in[6];
    const float* b3   = (const float*)d_in[7];
    float* out = (float*)d_out;
    int B = in_sizes[0] / 4;

    char* ws = (char*)d_ws;
    _Float16* W2F = (_Float16*)(ws);            // 262144 B
    _Float16* W3F = (_Float16*)(ws + 262144);   // 98304 B
    float4*   w1p = (float4*)(ws + 360448);     // 8192 B

    hipLaunchKernelGGL(prep_v24, dim3(354), dim3(256), 0, stream,
                       W1, b1, W2, W3, W2F, W3F, w1p);
    hipLaunchKernelGGL(rqs_v24, dim3(B / 32), dim3(64), 0, stream,
                       inp, cond, W2F, W3F, w1p, b2, b3, out, B);
}

// Round 14
// 236.747 us; speedup vs baseline: 1.0050x; 1.0050x over previous
//
#include <hip/hip_runtime.h>

#define TAILB 12.0f

typedef _Float16 half8 __attribute__((ext_vector_type(8)));
typedef _Float16 half4 __attribute__((ext_vector_type(4)));
typedef __fp16 fp16x2 __attribute__((ext_vector_type(2)));   // pkrtz return type
typedef __attribute__((ext_vector_type(4))) float f32x4;
typedef __attribute__((ext_vector_type(2))) float f32x2;

#define MFMAH __builtin_amdgcn_mfma_f32_16x16x32_f16

// soft phase fence (v22-proven): compile-time scheduling structure without
// runtime drains. mask 0x24 = SALU | VMEM_READ may cross; VALU/MFMA/DS
// pinned. Same-wave DS FIFO order guarantees correctness (v19).
#define SOFT_SYNC() __builtin_amdgcn_sched_barrier(0x24)

// fast softplus: log(1+e^z); abs err ~2^-24
__device__ __forceinline__ float softplus_f(float z) {
    return (z > 15.f) ? z : __logf(1.f + __expf(z));
}

// unscaled fp16 2-term split (v23-verified): RNE main, raw residual.
__device__ __forceinline__ void split2h(float v, _Float16& o0, _Float16& o1) {
    _Float16 h0 = (_Float16)v;
    float r1 = v - (float)h0;
    o0 = h0;
    o1 = (_Float16)r1;
}

// pkrtz-based unscaled split of 4 values -> two packed half4 planes
__device__ __forceinline__ void split4_ns(const float* v, half4& p0, half4& p1) {
    fp16x2 lo = __builtin_amdgcn_cvt_pkrtz(v[0], v[1]);
    fp16x2 hi = __builtin_amdgcn_cvt_pkrtz(v[2], v[3]);
    float r0 = v[0] - (float)lo.x;
    float r1 = v[1] - (float)lo.y;
    float r2 = v[2] - (float)hi.x;
    float r3 = v[3] - (float)hi.y;
    fp16x2 rlo = __builtin_amdgcn_cvt_pkrtz(r0, r1);
    fp16x2 rhi = __builtin_amdgcn_cvt_pkrtz(r2, r3);
    p0 = (half4){(_Float16)lo.x, (_Float16)lo.y, (_Float16)hi.x, (_Float16)hi.y};
    p1 = (half4){(_Float16)rlo.x, (_Float16)rlo.y, (_Float16)rhi.x, (_Float16)rhi.y};
}

// ---------------- prep: identical layout to v10..v24 ----------------
__global__ __launch_bounds__(256)
void prep_v25(const float* __restrict__ W1, const float* __restrict__ b1,
              const float* __restrict__ W2, const float* __restrict__ W3,
              _Float16* __restrict__ W2F, _Float16* __restrict__ W3F,
              float4* __restrict__ w1p)
{
    int id = blockIdx.x * 256 + threadIdx.x;
    if (id < 65536) {
        int j = id & 7, ln = (id >> 3) & 63, tile = id >> 9;
        int cs = tile & 3, t = (tile >> 2) & 1, wv = (tile >> 3) & 3, l = tile >> 5;
        int n = 32 * wv + 16 * t + (ln & 15);
        int k = 32 * cs + 8 * (ln >> 4) + j;
        _Float16 a, b;
        split2h(W2[l * 16384 + n * 128 + k], a, b);
        W2F[(tile * 2 + 0) * 512 + ln * 8 + j] = a;
        W2F[(tile * 2 + 1) * 512 + ln * 8 + j] = b;
    } else if (id < 90112) {
        int t2 = id - 65536;
        int j = t2 & 7, ln = (t2 >> 3) & 63, tile3 = t2 >> 9;
        int cs = tile3 & 3, q = tile3 >> 2;
        int wv = q % 3, l = q / 3;
        int p = 16 * wv + (ln & 15);
        int n = 32 * cs + 8 * (ln >> 4) + j;
        float v = (p < 46) ? W3[l * 5888 + p * 128 + n] : 0.f;
        _Float16 a, b;
        split2h(v, a, b);
        W3F[(tile3 * 2 + 0) * 512 + ln * 8 + j] = a;
        W3F[(tile3 * 2 + 1) * 512 + ln * 8 + j] = b;
    } else if (id < 90624) {
        int t = id - 90112;
        int l = t >> 7, k = t & 127;
        float4 v;
        v.x = W1[l * 384 + k * 3 + 0];
        v.y = W1[l * 384 + k * 3 + 1];
        v.z = W1[l * 384 + k * 3 + 2];
        v.w = b1[l * 128 + k];
        w1p[t] = v;
    }
}

// v25 = v24 (192-193us) repackaged as 4 INDEPENDENT waves per 256-thread
// workgroup. Occupancy record across the session: 4-wave WGs get ~3.4
// blocks/CU (v14: 13.6 waves), 1-wave WGs ~10 blocks (10 waves), 2-wave
// ~3.5 blocks (7 waves) -- the dispatcher gives multi-wave WGs a fixed
// ~3.4-block residency, so 4-wave packaging maximizes waves/CU. v14 was
// slow from barrier gang-scheduling, NOT its occupancy; here the waves
// share nothing (own LDS slice, no __syncthreads). LDS 4x8832=35328 B/
// block -> 4 blocks/CU fits (141KB) and VGPR tier (80 regs -> 16 waves)
// is hit exactly. Math bit-identical to v24 -> absmax 0.5.
__global__ __launch_bounds__(256)
void rqs_v25(const float* __restrict__ inp, const float* __restrict__ cond,
             const _Float16* __restrict__ W2F, const _Float16* __restrict__ W3F,
             const float4* __restrict__ w1p,
             const float* __restrict__ b2, const float* __restrict__ b3,
             float* __restrict__ out, int B)
{
    __shared__ __align__(16) char P[4][8192];  // per-wave: h2 planes; pbuf overlays
    __shared__ float xbuf[4][32][5];

    const int w  = threadIdx.x >> 6;           // wave in block (fully independent)
    const int ln = threadIdx.x & 63;           // wave-local lane
    char* plw = P[w];
    const char* pl = plw;
    float (*xb)[5] = xbuf[w];

    const int base = blockIdx.x * 128 + w * 32;
    const int sm   = ln & 15;
    const int qd   = ln >> 4;                  // 0..3
    const int s1   = ln & 31;                  // sample slot
    const int hi   = ln >> 5;                  // half index

    // b-frag read addresses (v16): row = 16st+sm, slot = (4csl+qd)^(row&7)
    int rdK[2][2];
    #pragma unroll
    for (int st = 0; st < 2; ++st)
        #pragma unroll
        for (int csl = 0; csl < 2; ++csl) {
            int row = 16 * st + sm;
            rdK[st][csl] = row * 128 + (((4 * csl + qd) ^ (row & 7)) << 4);
        }

    if (ln < 32) {
        float4 xi = reinterpret_cast<const float4*>(inp)[base + ln];
        xb[ln][0] = xi.x; xb[ln][1] = xi.y;
        xb[ln][2] = xi.z; xb[ln][3] = xi.w;
        xb[ln][4] = cond[base + ln];
    }
    float ladreg = 0.f;
    SOFT_SYNC();

    #pragma unroll 1
    for (int l = 0; l < 4; ++l) {
        int mi0, mi1, ii0, ii1;
        switch (l) {
            case 0:  mi0 = 0; mi1 = 2; ii0 = 1; ii1 = 3; break;
            case 1:  mi0 = 1; mi1 = 3; ii0 = 0; ii1 = 2; break;
            case 2:  mi0 = 0; mi1 = 1; ii0 = 2; ii1 = 3; break;
            default: mi0 = 2; mi1 = 3; ii0 = 0; ii1 = 1; break;
        }

        // ---- phase 1: h1 in B-frag layout, packed dual-FP32 over (st0,st1) ----
        half8 bf[2][4][2];                     // [st][cs][plane]
        {
            f32x2 m0p = {xb[sm][mi0],      xb[16 + sm][mi0]};
            f32x2 m1p = {xb[sm][mi1],      xb[16 + sm][mi1]};
            f32x2 ccp = {xb[sm][4],        xb[16 + sm][4]};
            const float4* w1l = w1p + l * 128;
            #pragma unroll
            for (int cs = 0; cs < 4; ++cs) {
                float v0[8], v1[8];
                #pragma unroll
                for (int j = 0; j < 8; ++j) {
                    float4 w4 = w1l[32 * cs + 8 * qd + j];   // shared by both samples
                    f32x2 a = {w4.w, w4.w};
                    a = __builtin_elementwise_fma((f32x2){w4.z, w4.z}, ccp, a);
                    a = __builtin_elementwise_fma((f32x2){w4.y, w4.y}, m1p, a);
                    a = __builtin_elementwise_fma((f32x2){w4.x, w4.x}, m0p, a);
                    a = __builtin_elementwise_max(a, (f32x2){0.f, 0.f});
                    v0[j] = a.x;
                    v1[j] = a.y;
                }
                half4 a0, a1, b0h, b1h;
                split4_ns(v0, a0, a1);
                split4_ns(v0 + 4, b0h, b1h);
                bf[0][cs][0] = (half8){a0.x, a0.y, a0.z, a0.w, b0h.x, b0h.y, b0h.z, b0h.w};
                bf[0][cs][1] = (half8){a1.x, a1.y, a1.z, a1.w, b1h.x, b1h.y, b1h.z, b1h.w};
                split4_ns(v1, a0, a1);
                split4_ns(v1 + 4, b0h, b1h);
                bf[1][cs][0] = (half8){a0.x, a0.y, a0.z, a0.w, b0h.x, b0h.y, b0h.z, b0h.w};
                bf[1][cs][1] = (half8){a1.x, a1.y, a1.z, a1.w, b1h.x, b1h.y, b1h.z, b1h.w};
            }
        }

        // ---- GEMM2: B from registers; single chained accumulator (v23) ----
        half8 bf3[2][4][2];                    // [st][cs][plane] -- full h2 in regs
        const half8* W2F8 = (const half8*)W2F;
        #pragma unroll
        for (int ntg = 0; ntg < 2; ++ntg) {
            #pragma unroll 1
            for (int ntl = 0; ntl < 4; ++ntl) {
                int nt = 4 * ntg + ntl;        // n-tile 0..7
                f32x4 acc[2];                  // [st]
                float4 bias = *(const float4*)(b2 + l * 128 + nt * 16 + 4 * qd);
                #pragma unroll
                for (int st = 0; st < 2; ++st)
                    acc[st] = (f32x4){bias.x, bias.y, bias.z, bias.w};
                __builtin_amdgcn_s_setprio(1);
                #pragma unroll
                for (int cs = 0; cs < 4; ++cs) {
                    int tile = l * 8 + nt;
                    half8 A0 = W2F8[((tile * 4 + cs) * 2 + 0) * 64 + ln];
                    half8 A1 = W2F8[((tile * 4 + cs) * 2 + 1) * 64 + ln];
                    #pragma unroll
                    for (int st = 0; st < 2; ++st) {
                        acc[st] = MFMAH(A0, bf[st][cs][0], acc[st], 0, 0, 0);
                        acc[st] = MFMAH(A0, bf[st][cs][1], acc[st], 0, 0, 0);
                        acc[st] = MFMAH(A1, bf[st][cs][0], acc[st], 0, 0, 0);
                    }
                }
                __builtin_amdgcn_s_setprio(0);
                // h2 epilogue: relu + unscaled split, write planes
                #pragma unroll
                for (int st = 0; st < 2; ++st) {
                    float v[4];
                    #pragma unroll
                    for (int r = 0; r < 4; ++r)
                        v[r] = fmaxf(acc[st][r], 0.f);
                    half4 p0, p1;
                    split4_ns(v, p0, p1);
                    int row = 16 * st + sm;
                    int gl  = 2 * ntl + (qd >> 1);   // local n-group in [0,8)
                    char* wp = plw + row * 128 + ((gl ^ (row & 7)) << 4) + ((qd & 1) << 3);
                    *(half4*)(wp)        = p0;
                    *(half4*)(wp + 4096) = p1;
                }
            }
            SOFT_SYNC();   // h2 n-half ready (DS order; no drain)
            #pragma unroll
            for (int st = 0; st < 2; ++st)
                #pragma unroll
                for (int csl = 0; csl < 2; ++csl) {
                    bf3[st][2 * ntg + csl][0] = *(const half8*)(pl + rdK[st][csl]);
                    bf3[st][2 * ntg + csl][1] = *(const half8*)(pl + rdK[st][csl] + 4096);
                }
            SOFT_SYNC();   // reads ordered before next-half writes (DS order)
        }

        // ---- GEMM3: single chained accumulator; pv = acc directly ----
        const half8* W3F8 = (const half8*)W3F;
        #pragma unroll 1
        for (int pt = 0; pt < 3; ++pt) {
            f32x4 a3[2];
            #pragma unroll
            for (int st = 0; st < 2; ++st)
                a3[st] = (f32x4){0.f, 0.f, 0.f, 0.f};
            __builtin_amdgcn_s_setprio(1);
            #pragma unroll
            for (int cs = 0; cs < 4; ++cs) {
                int q = (l * 3 + pt) * 4 + cs;
                half8 A0 = W3F8[(q * 2 + 0) * 64 + ln];
                half8 A1 = W3F8[(q * 2 + 1) * 64 + ln];
                #pragma unroll
                for (int st = 0; st < 2; ++st) {
                    a3[st] = MFMAH(A0, bf3[st][cs][0], a3[st], 0, 0, 0);
                    a3[st] = MFMAH(A0, bf3[st][cs][1], a3[st], 0, 0, 0);
                    a3[st] = MFMAH(A1, bf3[st][cs][0], a3[st], 0, 0, 0);
                }
            }
            __builtin_amdgcn_s_setprio(0);
            #pragma unroll
            for (int st = 0; st < 2; ++st) {
                float4 pv;
                pv.x = a3[st][0];
                pv.y = a3[st][1];
                pv.z = a3[st][2];
                pv.w = a3[st][3];
                *(float4*)(plw + (16 * st + sm) * 208 + (16 * pt + 4 * qd) * 4) = pv;
            }
        }
        SOFT_SYNC();   // params visible (DS order; no drain)

        // ---- spline: all 64 lanes, one spline each: f = hi, s = s1 ----
        {
            const float* b3l = b3 + l * 46;
            const float4* prow = (const float4*)(pl + s1 * 208);
            float pr[23];
            #pragma unroll
            for (int i = 0; i < 12; ++i) {
                float4 q = prow[i];
                pr[2 * i] = (hi ? q.y : q.x) + b3l[4 * i + hi];
                if (2 * i + 1 < 23)
                    pr[2 * i + 1] = (hi ? q.w : q.z) + b3l[4 * i + 2 + hi];
            }

            float xin = xb[s1][hi == 0 ? ii0 : ii1];

            float d[9];
            d[0] = 1.f; d[8] = 1.f;
            #pragma unroll
            for (int k = 1; k < 8; ++k) d[k] = 1e-6f + softplus_f(pr[16 + k - 1]);

            bool inside = (xin >= -TAILB) && (xin <= TAILB);
            float xc = fminf(fmaxf(xin, -TAILB), TAILB);

            float mw = pr[0], mh = pr[8];
            #pragma unroll
            for (int k = 1; k < 8; ++k) { mw = fmaxf(mw, pr[k]); mh = fmaxf(mh, pr[8 + k]); }
            float ew[8], eh[8], swm = 0.f, shm = 0.f;
            #pragma unroll
            for (int k = 0; k < 8; ++k) {
                ew[k] = __expf(pr[k] - mw);     swm += ew[k];
                eh[k] = __expf(pr[8 + k] - mh); shm += eh[k];
            }
            const float c1 = 1.f - 8e-6f;
            float isw = __fdividef(c1, swm), ish = __fdividef(c1, shm);

            float cum_w = 0.f, cum_h = 0.f;
            float cwk = -TAILB, chk = -TAILB;
            float s_cw = -TAILB, s_w = 2.f * TAILB, s_ch = -TAILB, s_h = 2.f * TAILB;
            float s_d0 = 1.f, s_d1 = d[1];
            #pragma unroll
            for (int k = 0; k < 8; ++k) {
                cum_w += fmaf(ew[k], isw, 1e-6f);
                cum_h += fmaf(eh[k], ish, 1e-6f);
                float cwn = (k == 7) ? TAILB : fmaf(2.f * TAILB, cum_w, -TAILB);
                float chn = (k == 7) ? TAILB : fmaf(2.f * TAILB, cum_h, -TAILB);
                bool ge = (xc >= cwk);
                s_cw = ge ? cwk : s_cw;  s_w = ge ? (cwn - cwk) : s_w;
                s_ch = ge ? chk : s_ch;  s_h = ge ? (chn - chk) : s_h;
                s_d0 = ge ? d[k] : s_d0; s_d1 = ge ? d[k + 1] : s_d1;
                cwk = cwn; chk = chn;
            }

            float rw    = __fdividef(1.f, s_w);
            float th    = (xc - s_cw) * rw;
            float delta = s_h * rw;
            float omt   = 1.f - th;
            float tomt  = th * omt;
            float num   = s_h * fmaf(delta, th * th, s_d0 * tomt);
            float den   = fmaf(s_d0 + s_d1 - 2.f * delta, tomt, delta);
            float y     = s_ch + __fdividef(num, den);
            float dnum  = delta * delta * (s_d1 * th * th + 2.f * delta * tomt + s_d0 * omt * omt);
            float lad   = __logf(dnum) - 2.f * __logf(den);

            xb[s1][hi == 0 ? ii0 : ii1] = inside ? y : xin;
            ladreg += inside ? lad : 0.f;
        }
        SOFT_SYNC();   // x updated + pbuf reads ordered before next layer's writes
    } // l

    float lsum = ladreg + __shfl(ladreg, (ln + 32) & 63, 64);
    if (ln < 32) {
        float4 xo;
        xo.x = xb[ln][0]; xo.y = xb[ln][1];
        xo.z = xb[ln][2]; xo.w = xb[ln][3];
        reinterpret_cast<float4*>(out)[base + ln] = xo;
        out[(size_t)B * 4 + base + ln] = lsum;
    }
}

extern "C" void kernel_launch(void* const* d_in, const int* in_sizes, int n_in,
                              void* d_out, int out_size, void* d_ws, size_t ws_size,
                              hipStream_t stream) {
    const float* inp  = (const float*)d_in[0];
    const float* cond = (const float*)d_in[1];
    const float* W1   = (const float*)d_in[2];
    const float* b1   = (const float*)d_in[3];
    const float* W2   = (const float*)d_in[4];
    const float* b2   = (const float*)d_in[5];
    const float* W3   = (const float*)d_in[6];
    const float* b3   = (const float*)d_in[7];
    float* out = (float*)d_out;
    int B = in_sizes[0] / 4;

    char* ws = (char*)d_ws;
    _Float16* W2F = (_Float16*)(ws);            // 262144 B
    _Float16* W3F = (_Float16*)(ws + 262144);   // 98304 B
    float4*   w1p = (float4*)(ws + 360448);     // 8192 B

    hipLaunchKernelGGL(prep_v25, dim3(354), dim3(256), 0, stream,
                       W1, b1, W2, W3, W2F, W3F, w1p);
    hipLaunchKernelGGL(rqs_v25, dim3(B / 128), dim3(256), 0, stream,
                       inp, cond, W2F, W3F, w1p, b2, b3, out, B);
}

// Round 15
// 232.958 us; speedup vs baseline: 1.0214x; 1.0163x over previous
//
#include <hip/hip_runtime.h>

#define TAILB 12.0f

typedef _Float16 half8 __attribute__((ext_vector_type(8)));
typedef _Float16 half4 __attribute__((ext_vector_type(4)));
typedef __fp16 fp16x2 __attribute__((ext_vector_type(2)));   // pkrtz return type
typedef __attribute__((ext_vector_type(4))) float f32x4;
typedef __attribute__((ext_vector_type(2))) float f32x2;

#define MFMAH __builtin_amdgcn_mfma_f32_16x16x32_f16

// soft phase fence (v22-proven): compile-time scheduling structure without
// runtime drains. mask 0x24 = SALU | VMEM_READ may cross; VALU/MFMA/DS
// pinned. Same-wave DS FIFO order guarantees correctness (v19).
#define SOFT_SYNC() __builtin_amdgcn_sched_barrier(0x24)

// fast softplus: log(1+e^z); abs err ~2^-24
__device__ __forceinline__ float softplus_f(float z) {
    return (z > 15.f) ? z : __logf(1.f + __expf(z));
}

// unscaled fp16 2-term split (v23-verified): RNE main, raw residual.
__device__ __forceinline__ void split2h(float v, _Float16& o0, _Float16& o1) {
    _Float16 h0 = (_Float16)v;
    float r1 = v - (float)h0;
    o0 = h0;
    o1 = (_Float16)r1;
}

// pkrtz-based unscaled split of 4 values -> two packed half4 planes
__device__ __forceinline__ void split4_ns(const float* v, half4& p0, half4& p1) {
    fp16x2 lo = __builtin_amdgcn_cvt_pkrtz(v[0], v[1]);
    fp16x2 hi = __builtin_amdgcn_cvt_pkrtz(v[2], v[3]);
    float r0 = v[0] - (float)lo.x;
    float r1 = v[1] - (float)lo.y;
    float r2 = v[2] - (float)hi.x;
    float r3 = v[3] - (float)hi.y;
    fp16x2 rlo = __builtin_amdgcn_cvt_pkrtz(r0, r1);
    fp16x2 rhi = __builtin_amdgcn_cvt_pkrtz(r2, r3);
    p0 = (half4){(_Float16)lo.x, (_Float16)lo.y, (_Float16)hi.x, (_Float16)hi.y};
    p1 = (half4){(_Float16)rlo.x, (_Float16)rlo.y, (_Float16)rhi.x, (_Float16)rhi.y};
}

// ---------------- prep: identical layout to v10..v25 ----------------
__global__ __launch_bounds__(256)
void prep_v26(const float* __restrict__ W1, const float* __restrict__ b1,
              const float* __restrict__ W2, const float* __restrict__ W3,
              _Float16* __restrict__ W2F, _Float16* __restrict__ W3F,
              float4* __restrict__ w1p)
{
    int id = blockIdx.x * 256 + threadIdx.x;
    if (id < 65536) {
        int j = id & 7, ln = (id >> 3) & 63, tile = id >> 9;
        int cs = tile & 3, t = (tile >> 2) & 1, wv = (tile >> 3) & 3, l = tile >> 5;
        int n = 32 * wv + 16 * t + (ln & 15);
        int k = 32 * cs + 8 * (ln >> 4) + j;
        _Float16 a, b;
        split2h(W2[l * 16384 + n * 128 + k], a, b);
        W2F[(tile * 2 + 0) * 512 + ln * 8 + j] = a;
        W2F[(tile * 2 + 1) * 512 + ln * 8 + j] = b;
    } else if (id < 90112) {
        int t2 = id - 65536;
        int j = t2 & 7, ln = (t2 >> 3) & 63, tile3 = t2 >> 9;
        int cs = tile3 & 3, q = tile3 >> 2;
        int wv = q % 3, l = q / 3;
        int p = 16 * wv + (ln & 15);
        int n = 32 * cs + 8 * (ln >> 4) + j;
        float v = (p < 46) ? W3[l * 5888 + p * 128 + n] : 0.f;
        _Float16 a, b;
        split2h(v, a, b);
        W3F[(tile3 * 2 + 0) * 512 + ln * 8 + j] = a;
        W3F[(tile3 * 2 + 1) * 512 + ln * 8 + j] = b;
    } else if (id < 90624) {
        int t = id - 90112;
        int l = t >> 7, k = t & 127;
        float4 v;
        v.x = W1[l * 384 + k * 3 + 0];
        v.y = W1[l * 384 + k * 3 + 1];
        v.z = W1[l * 384 + k * 3 + 2];
        v.w = b1[l * 128 + k];
        w1p[t] = v;
    }
}

// v26 = v24 (best: 192-193us, 1-wave blocks) with software-pipelining
// unlocked in the tile loops. Diagnosis: latency-bound at thin TLP (9.6
// waves/CU hard ceiling, ~67% per-wave stall), and GEMM2's n-tile loop ran
// at "#pragma unroll 1" -- every iteration serially exposes ~250cy of L2
// latency for its 8 A-tile loads before 12 chained MFMAs. unroll 2 lets
// the compiler interleave tile t+1's loads under tile t's MFMAs
// (independent accumulators); GEMM3's 3-iteration pt loop fully unrolls.
// ~11 exposed L2 windows/layer -> ~5. VGPR ~110-125, still >= 4 waves/SIMD
// tier (above the 9.6-wave ceiling). Math bit-identical -> absmax 0.5.
__global__ __launch_bounds__(64)
void rqs_v26(const float* __restrict__ inp, const float* __restrict__ cond,
             const _Float16* __restrict__ W2F, const _Float16* __restrict__ W3F,
             const float4* __restrict__ w1p,
             const float* __restrict__ b2, const float* __restrict__ b3,
             float* __restrict__ out, int B)
{
    __shared__ __align__(16) char P[8192];     // h2 planeA + planeB @4096; pbuf overlays
    __shared__ float xbuf[32][5];

    char* plw = P;
    const char* pl = P;

    const int ln   = threadIdx.x;              // 0..63
    const int base = blockIdx.x * 32;
    const int sm   = ln & 15;
    const int qd   = ln >> 4;                  // 0..3
    const int s1   = ln & 31;                  // sample slot
    const int hi   = ln >> 5;                  // half index

    // b-frag read addresses (v16): row = 16st+sm, slot = (4csl+qd)^(row&7)
    int rdK[2][2];
    #pragma unroll
    for (int st = 0; st < 2; ++st)
        #pragma unroll
        for (int csl = 0; csl < 2; ++csl) {
            int row = 16 * st + sm;
            rdK[st][csl] = row * 128 + (((4 * csl + qd) ^ (row & 7)) << 4);
        }

    if (ln < 32) {
        float4 xi = reinterpret_cast<const float4*>(inp)[base + ln];
        xbuf[ln][0] = xi.x; xbuf[ln][1] = xi.y;
        xbuf[ln][2] = xi.z; xbuf[ln][3] = xi.w;
        xbuf[ln][4] = cond[base + ln];
    }
    float ladreg = 0.f;
    SOFT_SYNC();

    #pragma unroll 1
    for (int l = 0; l < 4; ++l) {
        int mi0, mi1, ii0, ii1;
        switch (l) {
            case 0:  mi0 = 0; mi1 = 2; ii0 = 1; ii1 = 3; break;
            case 1:  mi0 = 1; mi1 = 3; ii0 = 0; ii1 = 2; break;
            case 2:  mi0 = 0; mi1 = 1; ii0 = 2; ii1 = 3; break;
            default: mi0 = 2; mi1 = 3; ii0 = 0; ii1 = 1; break;
        }

        // ---- phase 1: h1 in B-frag layout, packed dual-FP32 over (st0,st1) ----
        half8 bf[2][4][2];                     // [st][cs][plane]
        {
            f32x2 m0p = {xbuf[sm][mi0],      xbuf[16 + sm][mi0]};
            f32x2 m1p = {xbuf[sm][mi1],      xbuf[16 + sm][mi1]};
            f32x2 ccp = {xbuf[sm][4],        xbuf[16 + sm][4]};
            const float4* w1l = w1p + l * 128;
            #pragma unroll
            for (int cs = 0; cs < 4; ++cs) {
                float v0[8], v1[8];
                #pragma unroll
                for (int j = 0; j < 8; ++j) {
                    float4 w4 = w1l[32 * cs + 8 * qd + j];   // shared by both samples
                    f32x2 a = {w4.w, w4.w};
                    a = __builtin_elementwise_fma((f32x2){w4.z, w4.z}, ccp, a);
                    a = __builtin_elementwise_fma((f32x2){w4.y, w4.y}, m1p, a);
                    a = __builtin_elementwise_fma((f32x2){w4.x, w4.x}, m0p, a);
                    a = __builtin_elementwise_max(a, (f32x2){0.f, 0.f});
                    v0[j] = a.x;
                    v1[j] = a.y;
                }
                half4 a0, a1, b0h, b1h;
                split4_ns(v0, a0, a1);
                split4_ns(v0 + 4, b0h, b1h);
                bf[0][cs][0] = (half8){a0.x, a0.y, a0.z, a0.w, b0h.x, b0h.y, b0h.z, b0h.w};
                bf[0][cs][1] = (half8){a1.x, a1.y, a1.z, a1.w, b1h.x, b1h.y, b1h.z, b1h.w};
                split4_ns(v1, a0, a1);
                split4_ns(v1 + 4, b0h, b1h);
                bf[1][cs][0] = (half8){a0.x, a0.y, a0.z, a0.w, b0h.x, b0h.y, b0h.z, b0h.w};
                bf[1][cs][1] = (half8){a1.x, a1.y, a1.z, a1.w, b1h.x, b1h.y, b1h.z, b1h.w};
            }
        }

        // ---- GEMM2: B from registers; unroll 2 -> loads pipeline across tiles ----
        half8 bf3[2][4][2];                    // [st][cs][plane] -- full h2 in regs
        const half8* W2F8 = (const half8*)W2F;
        #pragma unroll
        for (int ntg = 0; ntg < 2; ++ntg) {
            #pragma unroll 2
            for (int ntl = 0; ntl < 4; ++ntl) {
                int nt = 4 * ntg + ntl;        // n-tile 0..7
                f32x4 acc[2];                  // [st]
                float4 bias = *(const float4*)(b2 + l * 128 + nt * 16 + 4 * qd);
                #pragma unroll
                for (int st = 0; st < 2; ++st)
                    acc[st] = (f32x4){bias.x, bias.y, bias.z, bias.w};
                __builtin_amdgcn_s_setprio(1);
                #pragma unroll
                for (int cs = 0; cs < 4; ++cs) {
                    int tile = l * 8 + nt;
                    half8 A0 = W2F8[((tile * 4 + cs) * 2 + 0) * 64 + ln];
                    half8 A1 = W2F8[((tile * 4 + cs) * 2 + 1) * 64 + ln];
                    #pragma unroll
                    for (int st = 0; st < 2; ++st) {
                        acc[st] = MFMAH(A0, bf[st][cs][0], acc[st], 0, 0, 0);
                        acc[st] = MFMAH(A0, bf[st][cs][1], acc[st], 0, 0, 0);
                        acc[st] = MFMAH(A1, bf[st][cs][0], acc[st], 0, 0, 0);
                    }
                }
                __builtin_amdgcn_s_setprio(0);
                // h2 epilogue: relu + unscaled split, write planes
                #pragma unroll
                for (int st = 0; st < 2; ++st) {
                    float v[4];
                    #pragma unroll
                    for (int r = 0; r < 4; ++r)
                        v[r] = fmaxf(acc[st][r], 0.f);
                    half4 p0, p1;
                    split4_ns(v, p0, p1);
                    int row = 16 * st + sm;
                    int gl  = 2 * ntl + (qd >> 1);   // local n-group in [0,8)
                    char* wp = plw + row * 128 + ((gl ^ (row & 7)) << 4) + ((qd & 1) << 3);
                    *(half4*)(wp)        = p0;
                    *(half4*)(wp + 4096) = p1;
                }
            }
            SOFT_SYNC();   // h2 n-half ready (DS order; no drain)
            #pragma unroll
            for (int st = 0; st < 2; ++st)
                #pragma unroll
                for (int csl = 0; csl < 2; ++csl) {
                    bf3[st][2 * ntg + csl][0] = *(const half8*)(pl + rdK[st][csl]);
                    bf3[st][2 * ntg + csl][1] = *(const half8*)(pl + rdK[st][csl] + 4096);
                }
            SOFT_SYNC();   // reads ordered before next-half writes (DS order)
        }

        // ---- GEMM3: fully unrolled p-tiles; pv = acc directly ----
        const half8* W3F8 = (const half8*)W3F;
        #pragma unroll
        for (int pt = 0; pt < 3; ++pt) {
            f32x4 a3[2];
            #pragma unroll
            for (int st = 0; st < 2; ++st)
                a3[st] = (f32x4){0.f, 0.f, 0.f, 0.f};
            __builtin_amdgcn_s_setprio(1);
            #pragma unroll
            for (int cs = 0; cs < 4; ++cs) {
                int q = (l * 3 + pt) * 4 + cs;
                half8 A0 = W3F8[(q * 2 + 0) * 64 + ln];
                half8 A1 = W3F8[(q * 2 + 1) * 64 + ln];
                #pragma unroll
                for (int st = 0; st < 2; ++st) {
                    a3[st] = MFMAH(A0, bf3[st][cs][0], a3[st], 0, 0, 0);
                    a3[st] = MFMAH(A0, bf3[st][cs][1], a3[st], 0, 0, 0);
                    a3[st] = MFMAH(A1, bf3[st][cs][0], a3[st], 0, 0, 0);
                }
            }
            __builtin_amdgcn_s_setprio(0);
            #pragma unroll
            for (int st = 0; st < 2; ++st) {
                float4 pv;
                pv.x = a3[st][0];
                pv.y = a3[st][1];
                pv.z = a3[st][2];
                pv.w = a3[st][3];
                *(float4*)(plw + (16 * st + sm) * 208 + (16 * pt + 4 * qd) * 4) = pv;
            }
        }
        SOFT_SYNC();   // params visible (DS order; no drain)

        // ---- spline: all 64 lanes, one spline each: f = hi, s = s1 ----
        {
            const float* b3l = b3 + l * 46;
            const float4* prow = (const float4*)(pl + s1 * 208);
            float pr[23];
            #pragma unroll
            for (int i = 0; i < 12; ++i) {
                float4 q = prow[i];
                pr[2 * i] = (hi ? q.y : q.x) + b3l[4 * i + hi];
                if (2 * i + 1 < 23)
                    pr[2 * i + 1] = (hi ? q.w : q.z) + b3l[4 * i + 2 + hi];
            }

            float xin = xbuf[s1][hi == 0 ? ii0 : ii1];

            float d[9];
            d[0] = 1.f; d[8] = 1.f;
            #pragma unroll
            for (int k = 1; k < 8; ++k) d[k] = 1e-6f + softplus_f(pr[16 + k - 1]);

            bool inside = (xin >= -TAILB) && (xin <= TAILB);
            float xc = fminf(fmaxf(xin, -TAILB), TAILB);

            float mw = pr[0], mh = pr[8];
            #pragma unroll
            for (int k = 1; k < 8; ++k) { mw = fmaxf(mw, pr[k]); mh = fmaxf(mh, pr[8 + k]); }
            float ew[8], eh[8], swm = 0.f, shm = 0.f;
            #pragma unroll
            for (int k = 0; k < 8; ++k) {
                ew[k] = __expf(pr[k] - mw);     swm += ew[k];
                eh[k] = __expf(pr[8 + k] - mh); shm += eh[k];
            }
            const float c1 = 1.f - 8e-6f;
            float isw = __fdividef(c1, swm), ish = __fdividef(c1, shm);

            float cum_w = 0.f, cum_h = 0.f;
            float cwk = -TAILB, chk = -TAILB;
            float s_cw = -TAILB, s_w = 2.f * TAILB, s_ch = -TAILB, s_h = 2.f * TAILB;
            float s_d0 = 1.f, s_d1 = d[1];
            #pragma unroll
            for (int k = 0; k < 8; ++k) {
                cum_w += fmaf(ew[k], isw, 1e-6f);
                cum_h += fmaf(eh[k], ish, 1e-6f);
                float cwn = (k == 7) ? TAILB : fmaf(2.f * TAILB, cum_w, -TAILB);
                float chn = (k == 7) ? TAILB : fmaf(2.f * TAILB, cum_h, -TAILB);
                bool ge = (xc >= cwk);
                s_cw = ge ? cwk : s_cw;  s_w = ge ? (cwn - cwk) : s_w;
                s_ch = ge ? chk : s_ch;  s_h = ge ? (chn - chk) : s_h;
                s_d0 = ge ? d[k] : s_d0; s_d1 = ge ? d[k + 1] : s_d1;
                cwk = cwn; chk = chn;
            }

            float rw    = __fdividef(1.f, s_w);
            float th    = (xc - s_cw) * rw;
            float delta = s_h * rw;
            float omt   = 1.f - th;
            float tomt  = th * omt;
            float num   = s_h * fmaf(delta, th * th, s_d0 * tomt);
            float den   = fmaf(s_d0 + s_d1 - 2.f * delta, tomt, delta);
            float y     = s_ch + __fdividef(num, den);
            float dnum  = delta * delta * (s_d1 * th * th + 2.f * delta * tomt + s_d0 * omt * omt);
            float lad   = __logf(dnum) - 2.f * __logf(den);

            xbuf[s1][hi == 0 ? ii0 : ii1] = inside ? y : xin;
            ladreg += inside ? lad : 0.f;
        }
        SOFT_SYNC();   // x updated + pbuf reads ordered before next layer's writes
    } // l

    float lsum = ladreg + __shfl(ladreg, (ln + 32) & 63, 64);
    if (ln < 32) {
        float4 xo;
        xo.x = xbuf[ln][0]; xo.y = xbuf[ln][1];
        xo.z = xbuf[ln][2]; xo.w = xbuf[ln][3];
        reinterpret_cast<float4*>(out)[base + ln] = xo;
        out[(size_t)B * 4 + base + ln] = lsum;
    }
}

extern "C" void kernel_launch(void* const* d_in, const int* in_sizes, int n_in,
                              void* d_out, int out_size, void* d_ws, size_t ws_size,
                              hipStream_t stream) {
    const float* inp  = (const float*)d_in[0];
    const float* cond = (const float*)d_in[1];
    const float* W1   = (const float*)d_in[2];
    const float* b1   = (const float*)d_in[3];
    const float* W2   = (const float*)d_in[4];
    const float* b2   = (const float*)d_in[5];
    const float* W3   = (const float*)d_in[6];
    const float* b3   = (const float*)d_in[7];
    float* out = (float*)d_out;
    int B = in_sizes[0] / 4;

    char* ws = (char*)d_ws;
    _Float16* W2F = (_Float16*)(ws);            // 262144 B
    _Float16* W3F = (_Float16*)(ws + 262144);   // 98304 B
    float4*   w1p = (float4*)(ws + 360448);     // 8192 B

    hipLaunchKernelGGL(prep_v26, dim3(354), dim3(256), 0, stream,
                       W1, b1, W2, W3, W2F, W3F, w1p);
    hipLaunchKernelGGL(rqs_v26, dim3(B / 32), dim3(64), 0, stream,
                       inp, cond, W2F, W3F, w1p, b2, b3, out, B);
}